// Round 1
// baseline (192.547 us; speedup 1.0000x reference)
//
#include <hip/hip_runtime.h>

// Problem constants
#define DD 1024   // latent dim
#define TT 64     // max words
#define RR 36     // regions
#define NBC 128   // captions
#define NBI 128   // images
#define HH 128    // mlp hidden

// ws layout (float offsets)
#define OFF_CAPR 0                    // cap_repr  [128*1024]
#define OFF_CAPU (128 * 1024)         // cap_unit  [128*1024]
#define OFF_S    (2 * 128 * 1024)     // region sums   [128*1024]
#define OFF_P    (3 * 128 * 1024)     // region sumsq  [128*1024]
#define OFF_G1   (4 * 128 * 1024)     // 1+gamma   [128*1024]
#define OFF_BETA (5 * 128 * 1024)     // beta      [128*1024]
#define OFF_A    (6 * 128 * 1024)     // rstd/36   [1024]
#define OFF_BV   (6 * 128 * 1024 + 1024) // mean*rstd [1024]

// ---------------------------------------------------------------------------
// K1: blocks 0..127  -> masked mean-pool of captions + l2norm (cap_repr, cap_unit)
//     blocks 128..255 -> per-(b,d) region sums + sumsq of img_embed
// ---------------------------------------------------------------------------
__global__ __launch_bounds__(256) void k_pool(const float* __restrict__ img,
                                              const float* __restrict__ cap,
                                              const int* __restrict__ lens,
                                              float* __restrict__ ws) {
    const int tid = threadIdx.x;          // 0..255, one float4 (4 channels) each
    const int blk = blockIdx.x;
    __shared__ float red[4];

    if (blk < NBC) {
        const int b = blk;
        const int len = lens[b];
        const float4* cp = (const float4*)(cap + (size_t)b * TT * DD);
        float4 acc = make_float4(0.f, 0.f, 0.f, 0.f);
        for (int w = 0; w < len; ++w) {
            float4 x = cp[w * (DD / 4) + tid];
            acc.x += x.x; acc.y += x.y; acc.z += x.z; acc.w += x.w;
        }
        const float inv = 1.0f / (float)len;
        acc.x *= inv; acc.y *= inv; acc.z *= inv; acc.w *= inv;
        ((float4*)(ws + OFF_CAPR + (size_t)b * DD))[tid] = acc;

        // block-wide sum of squares for l2norm
        float ss = acc.x * acc.x + acc.y * acc.y + acc.z * acc.z + acc.w * acc.w;
        #pragma unroll
        for (int o = 32; o; o >>= 1) ss += __shfl_xor(ss, o);
        if ((tid & 63) == 0) red[tid >> 6] = ss;
        __syncthreads();
        const float tot = red[0] + red[1] + red[2] + red[3];
        const float rn = rsqrtf(tot);
        float4 u = make_float4(acc.x * rn, acc.y * rn, acc.z * rn, acc.w * rn);
        ((float4*)(ws + OFF_CAPU + (size_t)b * DD))[tid] = u;
    } else {
        const int b = blk - NBC;
        const float4* ip = (const float4*)(img + (size_t)b * RR * DD);
        float4 s = make_float4(0.f, 0.f, 0.f, 0.f);
        float4 q = make_float4(0.f, 0.f, 0.f, 0.f);
        #pragma unroll 4
        for (int r = 0; r < RR; ++r) {
            float4 x = ip[r * (DD / 4) + tid];
            s.x += x.x; s.y += x.y; s.z += x.z; s.w += x.w;
            q.x = fmaf(x.x, x.x, q.x); q.y = fmaf(x.y, x.y, q.y);
            q.z = fmaf(x.z, x.z, q.z); q.w = fmaf(x.w, x.w, q.w);
        }
        ((float4*)(ws + OFF_S + (size_t)b * DD))[tid] = s;
        ((float4*)(ws + OFF_P + (size_t)b * DD))[tid] = q;
    }
}

// ---------------------------------------------------------------------------
// K2: block 0 -> channel stats:  A[d] = rstd/R,  Bv[d] = mean*rstd
//     blocks 1..32 -> both MLPs for 4 captions each:
//       g1 = 1 + mlp_g(cap_repr), beta = mlp_b(cap_repr)
// ---------------------------------------------------------------------------
__global__ __launch_bounds__(1024) void k_stats_mlp(
        const float* __restrict__ Wg1, const float* __restrict__ bg1,
        const float* __restrict__ Wg2, const float* __restrict__ bg2,
        const float* __restrict__ Wb1, const float* __restrict__ bb1,
        const float* __restrict__ Wb2, const float* __restrict__ bb2,
        float* __restrict__ ws) {
    const int tid = threadIdx.x;

    if (blockIdx.x == 0) {
        // per-channel stats over all 128*36 samples
        const int d = tid;                      // 0..1023
        const float* Sp = ws + OFF_S;
        const float* Pp = ws + OFF_P;
        float s = 0.f, q2 = 0.f;
        for (int b = 0; b < NBI; ++b) {
            s += Sp[(size_t)b * DD + d];
            q2 += Pp[(size_t)b * DD + d];
        }
        const float invN = 1.0f / (float)(NBI * RR);
        const float mean = s * invN;
        const float var = q2 * invN - mean * mean;
        const float rstd = rsqrtf(var + 1e-5f);
        ws[OFF_A + d] = rstd * (1.0f / (float)RR);
        ws[OFF_BV + d] = mean * rstd;
        return;
    }

    __shared__ float capL[4][DD];     // 16 KB
    __shared__ float hL[4][2][HH];    // 4 KB
    const int c0 = (blockIdx.x - 1) * 4;

    // stage 4 caption representations
    {
        const int c = tid >> 8;        // 0..3
        const int r = tid & 255;       // float4 index
        float4 v = ((const float4*)(ws + OFF_CAPR + (size_t)(c0 + c) * DD))[r];
        ((float4*)&capL[c][0])[r] = v;
    }
    __syncthreads();

    // layer 1: 1024 units = 4c x {gamma,beta} x 128 hidden; one per thread
    {
        const int c = tid >> 8;
        const int net = (tid >> 7) & 1;       // 0 = gamma-net, 1 = beta-net
        const int j = tid & 127;
        const float* W1 = net ? Wb1 : Wg1;
        const float4* capc = (const float4*)&capL[c][0];
        float a0 = 0.f, a1 = 0.f, a2 = 0.f, a3 = 0.f;
        #pragma unroll 4
        for (int d4i = 0; d4i < DD / 4; ++d4i) {
            const float4 cv = capc[d4i];
            const int db = d4i * 4;
            a0 = fmaf(W1[(db + 0) * HH + j], cv.x, a0);
            a1 = fmaf(W1[(db + 1) * HH + j], cv.y, a1);
            a2 = fmaf(W1[(db + 2) * HH + j], cv.z, a2);
            a3 = fmaf(W1[(db + 3) * HH + j], cv.w, a3);
        }
        const float h = (a0 + a1) + (a2 + a3) + (net ? bb1[j] : bg1[j]);
        hL[c][net][j] = fmaxf(h, 0.0f);
    }
    __syncthreads();

    // layer 2: each thread -> one caption c, 4 consecutive channels, both nets
    {
        const int c = tid >> 8;
        const int d4 = tid & 255;
        float4 ag = make_float4(0.f, 0.f, 0.f, 0.f);
        float4 ab = make_float4(0.f, 0.f, 0.f, 0.f);
        #pragma unroll 4
        for (int j = 0; j < HH; ++j) {
            const float4 wg = ((const float4*)(Wg2 + (size_t)j * DD))[d4];
            const float4 wb = ((const float4*)(Wb2 + (size_t)j * DD))[d4];
            const float hg = hL[c][0][j];
            const float hb = hL[c][1][j];
            ag.x = fmaf(hg, wg.x, ag.x); ag.y = fmaf(hg, wg.y, ag.y);
            ag.z = fmaf(hg, wg.z, ag.z); ag.w = fmaf(hg, wg.w, ag.w);
            ab.x = fmaf(hb, wb.x, ab.x); ab.y = fmaf(hb, wb.y, ab.y);
            ab.z = fmaf(hb, wb.z, ab.z); ab.w = fmaf(hb, wb.w, ab.w);
        }
        const float4 bgv = ((const float4*)bg2)[d4];
        const float4 bbv = ((const float4*)bb2)[d4];
        const float4 g1v = make_float4(1.f + ag.x + bgv.x, 1.f + ag.y + bgv.y,
                                       1.f + ag.z + bgv.z, 1.f + ag.w + bgv.w);
        const float4 bev = make_float4(ab.x + bbv.x, ab.y + bbv.y,
                                       ab.z + bbv.z, ab.w + bbv.w);
        ((float4*)(ws + OFF_G1 + (size_t)(c0 + c) * DD))[d4] = g1v;
        ((float4*)(ws + OFF_BETA + (size_t)(c0 + c) * DD))[d4] = bev;
    }
}

// ---------------------------------------------------------------------------
// K3: sims[b,c].  Grid (c=128, bgroup=4) x 256 threads (4 waves).
// Per-lane coefficient fold:  v[d] = S[b,d]*AG[d] + BB[d],
//   AG = A*g1,  BB = beta - Bv*g1.   out[b,c] = dot(v,cu)*rsqrt(sum v^2)
// ---------------------------------------------------------------------------
__global__ __launch_bounds__(256) void k_sims(const float* __restrict__ ws,
                                              float* __restrict__ out) {
    const int c = blockIdx.x;
    const int bg = blockIdx.y;
    const int lane = threadIdx.x & 63;
    const int w = threadIdx.x >> 6;

    const float4* Ap = (const float4*)(ws + OFF_A);
    const float4* Bp = (const float4*)(ws + OFF_BV);
    const float4* Gp = (const float4*)(ws + OFF_G1 + (size_t)c * DD);
    const float4* Ep = (const float4*)(ws + OFF_BETA + (size_t)c * DD);
    const float4* Up = (const float4*)(ws + OFF_CAPU + (size_t)c * DD);

    float4 AG[4], BB[4], CU[4];
    #pragma unroll
    for (int i = 0; i < 4; ++i) {
        const int idx = i * 64 + lane;
        const float4 a = Ap[idx];
        const float4 bv = Bp[idx];
        const float4 g = Gp[idx];
        const float4 be = Ep[idx];
        AG[i] = make_float4(a.x * g.x, a.y * g.y, a.z * g.z, a.w * g.w);
        BB[i] = make_float4(be.x - bv.x * g.x, be.y - bv.y * g.y,
                            be.z - bv.z * g.z, be.w - bv.w * g.w);
        CU[i] = Up[idx];
    }

    const float4* Sp = (const float4*)(ws + OFF_S);
    #pragma unroll
    for (int ib = 0; ib < 8; ++ib) {
        const int b = bg * 32 + w * 8 + ib;
        float dot = 0.f, ss = 0.f;
        #pragma unroll
        for (int i = 0; i < 4; ++i) {
            const float4 s4 = Sp[(size_t)b * (DD / 4) + i * 64 + lane];
            const float vx = fmaf(s4.x, AG[i].x, BB[i].x);
            const float vy = fmaf(s4.y, AG[i].y, BB[i].y);
            const float vz = fmaf(s4.z, AG[i].z, BB[i].z);
            const float vw = fmaf(s4.w, AG[i].w, BB[i].w);
            ss = fmaf(vx, vx, fmaf(vy, vy, fmaf(vz, vz, fmaf(vw, vw, ss))));
            dot = fmaf(vx, CU[i].x, fmaf(vy, CU[i].y,
                  fmaf(vz, CU[i].z, fmaf(vw, CU[i].w, dot))));
        }
        #pragma unroll
        for (int o = 32; o; o >>= 1) {
            dot += __shfl_xor(dot, o);
            ss += __shfl_xor(ss, o);
        }
        if (lane == 0) out[b * NBC + c] = dot * rsqrtf(ss);
    }
}

// ---------------------------------------------------------------------------
extern "C" void kernel_launch(void* const* d_in, const int* in_sizes, int n_in,
                              void* d_out, int out_size, void* d_ws, size_t ws_size,
                              hipStream_t stream) {
    const float* img = (const float*)d_in[0];
    const float* cap = (const float*)d_in[1];
    const int* lens  = (const int*)d_in[2];
    const float* Wg1 = (const float*)d_in[3];
    const float* bg1 = (const float*)d_in[4];
    const float* Wg2 = (const float*)d_in[5];
    const float* bg2 = (const float*)d_in[6];
    const float* Wb1 = (const float*)d_in[7];
    const float* bb1 = (const float*)d_in[8];
    const float* Wb2 = (const float*)d_in[9];
    const float* bb2 = (const float*)d_in[10];
    float* ws = (float*)d_ws;
    float* out = (float*)d_out;

    hipLaunchKernelGGL(k_pool, dim3(256), dim3(256), 0, stream, img, cap, lens, ws);
    hipLaunchKernelGGL(k_stats_mlp, dim3(33), dim3(1024), 0, stream,
                       Wg1, bg1, Wg2, bg2, Wb1, bb1, Wb2, bb2, ws);
    hipLaunchKernelGGL(k_sims, dim3(128, 4), dim3(256), 0, stream, ws, out);
}

// Round 2
// 128.460 us; speedup vs baseline: 1.4989x; 1.4989x over previous
//
#include <hip/hip_runtime.h>

// Problem constants
#define DD 1024   // latent dim
#define TT 64     // max words
#define RR 36     // regions
#define NBC 128   // captions
#define NBI 128   // images
#define HH 128    // mlp hidden

// ws layout (float offsets)
#define OFF_CAPR 0                    // cap_repr  [128*1024]
#define OFF_CAPU (128 * 1024)         // cap_unit  [128*1024]
#define OFF_S    (2 * 128 * 1024)     // region sums   [128*1024]
#define OFF_P    (3 * 128 * 1024)     // region sumsq  [128*1024]
#define OFF_G1   (4 * 128 * 1024)     // 1+gamma   [128*1024]
#define OFF_BETA (5 * 128 * 1024)     // beta      [128*1024]
#define OFF_A    (6 * 128 * 1024)     // rstd/36   [1024]
#define OFF_BV   (6 * 128 * 1024 + 1024)  // mean*rstd [1024]
#define OFF_H    (6 * 128 * 1024 + 2048)  // relu'd hidden [128c][2net][128j]

__device__ __forceinline__ float4 f4add(float4 a, float4 b) {
    return make_float4(a.x + b.x, a.y + b.y, a.z + b.z, a.w + b.w);
}

// ---------------------------------------------------------------------------
// K1: blocks 0..127  -> masked mean-pool of captions + l2norm (cap_repr, cap_unit)
//     blocks 128..255 -> per-(b,d) region sums + sumsq of img_embed
// Unrolled so >=8 wave-loads are in flight (was ~1 with the dynamic loop).
// ---------------------------------------------------------------------------
__global__ __launch_bounds__(256) void k_pool(const float* __restrict__ img,
                                              const float* __restrict__ cap,
                                              const int* __restrict__ lens,
                                              float* __restrict__ ws) {
    const int tid = threadIdx.x;          // one float4 (4 channels) each
    const int blk = blockIdx.x;
    __shared__ float red[4];

    if (blk < NBC) {
        const int b = blk;
        const int len = lens[b];
        const float4* cp = (const float4*)(cap + (size_t)b * TT * DD);
        float4 a0 = make_float4(0.f, 0.f, 0.f, 0.f);
        float4 a1 = a0, a2 = a0, a3 = a0, a4 = a0, a5 = a0, a6 = a0, a7 = a0;
        int w = 0;
        for (; w + 8 <= len; w += 8) {
            const float4* p = cp + (size_t)w * (DD / 4) + tid;
            float4 x0 = p[0 * (DD / 4)];
            float4 x1 = p[1 * (DD / 4)];
            float4 x2 = p[2 * (DD / 4)];
            float4 x3 = p[3 * (DD / 4)];
            float4 x4 = p[4 * (DD / 4)];
            float4 x5 = p[5 * (DD / 4)];
            float4 x6 = p[6 * (DD / 4)];
            float4 x7 = p[7 * (DD / 4)];
            a0 = f4add(a0, x0); a1 = f4add(a1, x1);
            a2 = f4add(a2, x2); a3 = f4add(a3, x3);
            a4 = f4add(a4, x4); a5 = f4add(a5, x5);
            a6 = f4add(a6, x6); a7 = f4add(a7, x7);
        }
        for (; w < len; ++w) a0 = f4add(a0, cp[(size_t)w * (DD / 4) + tid]);
        float4 acc = f4add(f4add(f4add(a0, a1), f4add(a2, a3)),
                           f4add(f4add(a4, a5), f4add(a6, a7)));
        const float inv = 1.0f / (float)len;
        acc.x *= inv; acc.y *= inv; acc.z *= inv; acc.w *= inv;
        ((float4*)(ws + OFF_CAPR + (size_t)b * DD))[tid] = acc;

        // block-wide sum of squares for l2norm
        float ss = acc.x * acc.x + acc.y * acc.y + acc.z * acc.z + acc.w * acc.w;
        #pragma unroll
        for (int o = 32; o; o >>= 1) ss += __shfl_xor(ss, o);
        if ((tid & 63) == 0) red[tid >> 6] = ss;
        __syncthreads();
        const float tot = red[0] + red[1] + red[2] + red[3];
        const float rn = rsqrtf(tot);
        float4 u = make_float4(acc.x * rn, acc.y * rn, acc.z * rn, acc.w * rn);
        ((float4*)(ws + OFF_CAPU + (size_t)b * DD))[tid] = u;
    } else {
        const int b = blk - NBC;
        const float4* ip = (const float4*)(img + (size_t)b * RR * DD);
        float4 s0 = make_float4(0.f, 0.f, 0.f, 0.f), s1 = s0;
        float4 q0 = s0, q1 = s0;
        #pragma unroll 3
        for (int r = 0; r < RR; r += 2) {
            float4 x = ip[r * (DD / 4) + tid];
            float4 y = ip[(r + 1) * (DD / 4) + tid];
            s0 = f4add(s0, x);
            q0.x = fmaf(x.x, x.x, q0.x); q0.y = fmaf(x.y, x.y, q0.y);
            q0.z = fmaf(x.z, x.z, q0.z); q0.w = fmaf(x.w, x.w, q0.w);
            s1 = f4add(s1, y);
            q1.x = fmaf(y.x, y.x, q1.x); q1.y = fmaf(y.y, y.y, q1.y);
            q1.z = fmaf(y.z, y.z, q1.z); q1.w = fmaf(y.w, y.w, q1.w);
        }
        ((float4*)(ws + OFF_S + (size_t)b * DD))[tid] = f4add(s0, s1);
        ((float4*)(ws + OFF_P + (size_t)b * DD))[tid] = f4add(q0, q1);
    }
}

// ---------------------------------------------------------------------------
// K2: MLP layer 1. blocks 0..255 = (cgroup:16 x net:2 x jslice:8 of 16 units).
// Each block reads its 64 KB W1 slice exactly once (no per-wave redundancy),
// amortized over 8 captions staged in LDS. Thread = (j within slice, k-chunk).
// blocks 256..271: channel stats -> A[d]=rstd/R, BV[d]=mean*rstd.
// ---------------------------------------------------------------------------
__global__ __launch_bounds__(256) void k_mlp1(
        const float* __restrict__ Wg1, const float* __restrict__ bg1,
        const float* __restrict__ Wb1, const float* __restrict__ bb1,
        float* __restrict__ ws) {
    const int blk = blockIdx.x;
    const int tid = threadIdx.x;

    if (blk >= 256) {
        // ---- channel stats over 128*36 samples, 64 channels per block ----
        const int dl = tid & 63;
        const int d = (blk - 256) * 64 + dl;
        const int bq = tid >> 6;              // 0..3
        float s = 0.f, q = 0.f;
        #pragma unroll 4
        for (int i = 0; i < 32; ++i) {
            const int b = bq * 32 + i;
            s += ws[OFF_S + (size_t)b * DD + d];
            q += ws[OFF_P + (size_t)b * DD + d];
        }
        __shared__ float rs[4][64], rq[4][64];
        rs[bq][dl] = s; rq[bq][dl] = q;
        __syncthreads();
        if (bq == 0) {
            s = rs[0][dl] + rs[1][dl] + rs[2][dl] + rs[3][dl];
            q = rq[0][dl] + rq[1][dl] + rq[2][dl] + rq[3][dl];
            const float invN = 1.0f / (float)(NBI * RR);
            const float mean = s * invN;
            const float var = q * invN - mean * mean;
            const float rstd = rsqrtf(var + 1e-5f);
            ws[OFF_A + d] = rstd * (1.0f / (float)RR);
            ws[OFF_BV + d] = mean * rstd;
        }
        return;
    }

    // ---- layer 1 ----
    const int cg = blk >> 4;                  // 0..15
    const int net = (blk >> 3) & 1;           // 0=gamma 1=beta
    const int jq = blk & 7;                   // j-slice
    const int c0 = cg * 8, j0 = jq * 16;
    const int j16 = tid & 15;                 // j within slice
    const int ks = tid >> 4;                  // 0..15, k-chunk (interleaved d)
    const float* __restrict__ W1 = net ? Wb1 : Wg1;
    const float* __restrict__ b1 = net ? bb1 : bg1;

    __shared__ float capL[8][DD];             // 32 KB
    {
        const float4* src = (const float4*)(ws + OFF_CAPR);
        #pragma unroll
        for (int i = 0; i < 8; ++i) {
            const int idx = i * 256 + tid;    // 0..2047
            const int c = idx >> 8, f4 = idx & 255;
            ((float4*)&capL[c][0])[f4] = src[(size_t)(c0 + c) * 256 + f4];
        }
    }
    __syncthreads();

    float a[8] = {0.f, 0.f, 0.f, 0.f, 0.f, 0.f, 0.f, 0.f};
    #pragma unroll
    for (int i = 0; i < 16; ++i) {
        const int d = i * 64 + ks * 4;        // 4 consecutive rows per chunk step
        const float w0 = W1[(size_t)(d + 0) * HH + j0 + j16];
        const float w1 = W1[(size_t)(d + 1) * HH + j0 + j16];
        const float w2 = W1[(size_t)(d + 2) * HH + j0 + j16];
        const float w3 = W1[(size_t)(d + 3) * HH + j0 + j16];
        #pragma unroll
        for (int c = 0; c < 8; ++c) {
            const float4 cv = *(const float4*)&capL[c][d];
            a[c] = fmaf(w0, cv.x, a[c]);
            a[c] = fmaf(w1, cv.y, a[c]);
            a[c] = fmaf(w2, cv.z, a[c]);
            a[c] = fmaf(w3, cv.w, a[c]);
        }
    }
    // reduce over ks: bits 4-5 of lane via shuffle, then 4 waves via LDS
    #pragma unroll
    for (int c = 0; c < 8; ++c) {
        a[c] += __shfl_xor(a[c], 16);
        a[c] += __shfl_xor(a[c], 32);
    }
    __shared__ float part[4][16][8];          // [wave][j16][c]
    const int wv = tid >> 6;
    if ((tid & 48) == 0) {
        #pragma unroll
        for (int c = 0; c < 8; ++c) part[wv][j16][c] = a[c];
    }
    __syncthreads();
    if (tid < 128) {
        const int cc = tid >> 4, jj = tid & 15;
        float h = part[0][jj][cc] + part[1][jj][cc] + part[2][jj][cc] +
                  part[3][jj][cc] + b1[j0 + jj];
        h = fmaxf(h, 0.0f);
        ws[OFF_H + ((size_t)(c0 + cc) * 2 + net) * HH + j0 + jj] = h;
    }
}

// ---------------------------------------------------------------------------
// K3: MLP layer 2. blocks = (cgroup:16 x net:2 x chan-slice:8 of 128).
// 64 KB W2 slice per block, each element loaded once; h broadcast from LDS.
// Writes g1 = 1+gamma (net 0) or beta (net 1).
// ---------------------------------------------------------------------------
__global__ __launch_bounds__(256) void k_mlp2(
        const float* __restrict__ Wg2, const float* __restrict__ bg2,
        const float* __restrict__ Wb2, const float* __restrict__ bb2,
        float* __restrict__ ws) {
    const int blk = blockIdx.x;
    const int cg = blk >> 4;
    const int net = (blk >> 3) & 1;
    const int dq = blk & 7;
    const int c0 = cg * 8, ch0 = dq * 128;
    const int tid = threadIdx.x;
    const float* __restrict__ W2 = net ? Wb2 : Wg2;
    const float* __restrict__ b2 = net ? bb2 : bg2;

    __shared__ float hL[8][HH];               // 4 KB
    {
        const int c = tid >> 5, j4 = tid & 31;
        ((float4*)&hL[c][0])[j4] =
            ((const float4*)(ws + OFF_H + ((size_t)(c0 + c) * 2 + net) * HH))[j4];
    }
    __syncthreads();

    const int c = tid >> 5, q = tid & 31;
    const int ch = ch0 + q * 4;
    float4 acA = make_float4(0.f, 0.f, 0.f, 0.f);
    float4 acB = acA, acC = acA, acD = acA;
    #pragma unroll 2
    for (int j = 0; j < HH; j += 4) {
        const float4 w0 = *(const float4*)&W2[(size_t)(j + 0) * DD + ch];
        const float4 w1 = *(const float4*)&W2[(size_t)(j + 1) * DD + ch];
        const float4 w2 = *(const float4*)&W2[(size_t)(j + 2) * DD + ch];
        const float4 w3 = *(const float4*)&W2[(size_t)(j + 3) * DD + ch];
        const float h0 = hL[c][j + 0], h1 = hL[c][j + 1];
        const float h2 = hL[c][j + 2], h3 = hL[c][j + 3];
        acA.x = fmaf(h0, w0.x, acA.x); acA.y = fmaf(h0, w0.y, acA.y);
        acA.z = fmaf(h0, w0.z, acA.z); acA.w = fmaf(h0, w0.w, acA.w);
        acB.x = fmaf(h1, w1.x, acB.x); acB.y = fmaf(h1, w1.y, acB.y);
        acB.z = fmaf(h1, w1.z, acB.z); acB.w = fmaf(h1, w1.w, acB.w);
        acC.x = fmaf(h2, w2.x, acC.x); acC.y = fmaf(h2, w2.y, acC.y);
        acC.z = fmaf(h2, w2.z, acC.z); acC.w = fmaf(h2, w2.w, acC.w);
        acD.x = fmaf(h3, w3.x, acD.x); acD.y = fmaf(h3, w3.y, acD.y);
        acD.z = fmaf(h3, w3.z, acD.z); acD.w = fmaf(h3, w3.w, acD.w);
    }
    float4 acc = f4add(f4add(acA, acB), f4add(acC, acD));
    const float4 bv = *(const float4*)&b2[ch];
    if (net == 0) {
        float4 g = make_float4(1.f + acc.x + bv.x, 1.f + acc.y + bv.y,
                               1.f + acc.z + bv.z, 1.f + acc.w + bv.w);
        *(float4*)(ws + OFF_G1 + (size_t)(c0 + c) * DD + ch) = g;
    } else {
        float4 be = make_float4(acc.x + bv.x, acc.y + bv.y,
                                acc.z + bv.z, acc.w + bv.w);
        *(float4*)(ws + OFF_BETA + (size_t)(c0 + c) * DD + ch) = be;
    }
}

// ---------------------------------------------------------------------------
// K4: sims[b,c].  Grid (c=128, bgroup=4) x 256 threads (4 waves).
// Per-lane coefficient fold:  v[d] = S[b,d]*AG[d] + BB[d],
//   AG = A*g1,  BB = beta - Bv*g1.   out[b,c] = dot(v,cu)*rsqrt(sum v^2)
// ---------------------------------------------------------------------------
__global__ __launch_bounds__(256) void k_sims(const float* __restrict__ ws,
                                              float* __restrict__ out) {
    const int c = blockIdx.x;
    const int bg = blockIdx.y;
    const int lane = threadIdx.x & 63;
    const int w = threadIdx.x >> 6;

    const float4* Ap = (const float4*)(ws + OFF_A);
    const float4* Bp = (const float4*)(ws + OFF_BV);
    const float4* Gp = (const float4*)(ws + OFF_G1 + (size_t)c * DD);
    const float4* Ep = (const float4*)(ws + OFF_BETA + (size_t)c * DD);
    const float4* Up = (const float4*)(ws + OFF_CAPU + (size_t)c * DD);

    float4 AG[4], BB[4], CU[4];
    #pragma unroll
    for (int i = 0; i < 4; ++i) {
        const int idx = i * 64 + lane;
        const float4 a = Ap[idx];
        const float4 bv = Bp[idx];
        const float4 g = Gp[idx];
        const float4 be = Ep[idx];
        AG[i] = make_float4(a.x * g.x, a.y * g.y, a.z * g.z, a.w * g.w);
        BB[i] = make_float4(be.x - bv.x * g.x, be.y - bv.y * g.y,
                            be.z - bv.z * g.z, be.w - bv.w * g.w);
        CU[i] = Up[idx];
    }

    const float4* Sp = (const float4*)(ws + OFF_S);
    #pragma unroll
    for (int ib = 0; ib < 8; ++ib) {
        const int b = bg * 32 + w * 8 + ib;
        float dot = 0.f, ss = 0.f;
        #pragma unroll
        for (int i = 0; i < 4; ++i) {
            const float4 s4 = Sp[(size_t)b * (DD / 4) + i * 64 + lane];
            const float vx = fmaf(s4.x, AG[i].x, BB[i].x);
            const float vy = fmaf(s4.y, AG[i].y, BB[i].y);
            const float vz = fmaf(s4.z, AG[i].z, BB[i].z);
            const float vw = fmaf(s4.w, AG[i].w, BB[i].w);
            ss = fmaf(vx, vx, fmaf(vy, vy, fmaf(vz, vz, fmaf(vw, vw, ss))));
            dot = fmaf(vx, CU[i].x, fmaf(vy, CU[i].y,
                  fmaf(vz, CU[i].z, fmaf(vw, CU[i].w, dot))));
        }
        #pragma unroll
        for (int o = 32; o; o >>= 1) {
            dot += __shfl_xor(dot, o);
            ss += __shfl_xor(ss, o);
        }
        if (lane == 0) out[b * NBC + c] = dot * rsqrtf(ss);
    }
}

// ---------------------------------------------------------------------------
extern "C" void kernel_launch(void* const* d_in, const int* in_sizes, int n_in,
                              void* d_out, int out_size, void* d_ws, size_t ws_size,
                              hipStream_t stream) {
    const float* img = (const float*)d_in[0];
    const float* cap = (const float*)d_in[1];
    const int* lens  = (const int*)d_in[2];
    const float* Wg1 = (const float*)d_in[3];
    const float* bg1 = (const float*)d_in[4];
    const float* Wg2 = (const float*)d_in[5];
    const float* bg2 = (const float*)d_in[6];
    const float* Wb1 = (const float*)d_in[7];
    const float* bb1 = (const float*)d_in[8];
    const float* Wb2 = (const float*)d_in[9];
    const float* bb2 = (const float*)d_in[10];
    float* ws = (float*)d_ws;
    float* out = (float*)d_out;

    hipLaunchKernelGGL(k_pool, dim3(256), dim3(256), 0, stream, img, cap, lens, ws);
    hipLaunchKernelGGL(k_mlp1, dim3(272), dim3(256), 0, stream,
                       Wg1, bg1, Wb1, bb1, ws);
    hipLaunchKernelGGL(k_mlp2, dim3(256), dim3(256), 0, stream,
                       Wg2, bg2, Wb2, bb2, ws);
    hipLaunchKernelGGL(k_sims, dim3(128, 4), dim3(256), 0, stream, ws, out);
}